// Round 8
// baseline (577.446 us; speedup 1.0000x reference)
//
#include <hip/hip_runtime.h>

// ---------------------------------------------------------------------------
// LoRA QKV fused projection on MI355X (gfx950)
// Weff-folding (LoRA into weights) + ONE bf16 MFMA GEMM (16x16x32 frags).
// R8 (rebased on R4 = best measured, 397us GEMM):
//  - one phase per K-slice: 12 ds_read_b128 + 4 global_load_lds + barrier +
//    lgkmcnt(0) + 32 MFMA + vmcnt(8) + barrier  (halves sync ops per slice)
//  - k-major LDS blocks: each 16-row group stored k-major so every frag read
//    is base + lane*16 (contiguous 1KB, conflict-free, no swizzle VALU)
//  - elastic uniform vmcnt(8) per phase (retired slice was issued 2 phases
//    earlier; queue 12->8, never drained in main loop)
// ---------------------------------------------------------------------------

#define GLOBAL_AS __attribute__((address_space(1)))
#define LDS_AS    __attribute__((address_space(3)))

typedef __attribute__((ext_vector_type(8))) short  short8;   // 8 bf16 (MFMA A/B frag)
typedef __attribute__((ext_vector_type(4))) float  floatx4;  // MFMA C/D frag

constexpr int Mdim = 8192;   // B*S
constexpr int Kdim = 4096;   // H
constexpr int NQ   = 4096;
constexpr int NKV  = 1024;
constexpr int NTOT = NQ + 2 * NKV;  // 6144
constexpr float LORA_SCALE = 2.0f;

constexpr int BM = 256, BN = 256;
constexpr int TILES_M = Mdim / BM;      // 32
constexpr int TILES_N = NTOT / BN;      // 24
constexpr int NWG = TILES_M * TILES_N;  // 768 (%8==0 -> bijective XCD swizzle)
constexpr int NSLICE = Kdim / 32;       // 128 K-slices of 32

constexpr int WEFF_BLOCKS = (NTOT / 64) * (Kdim / 512);  // 768
constexpr int CVT_BLOCKS  = 2048;
constexpr int AT_STRIDE   = 516;

__device__ __forceinline__ unsigned short f2bf(float f) {
    union { float f; unsigned int u; } a; a.f = f;
    unsigned int r = a.u + 0x7FFFu + ((a.u >> 16) & 1u);
    return (unsigned short)(r >> 16);
}

// ---------------------------------------------------------------------------
// Fused prep (identical to R4/R7 — linear outputs):
//   blocks [0, WEFF_BLOCKS): Weff[n,h] = W[n,h] + 2*sum_r A[h,r]B[r,n] -> bf16
//   blocks [WEFF_BLOCKS, +CVT_BLOCKS): X fp32 -> bf16.
// ---------------------------------------------------------------------------
__global__ __launch_bounds__(256)
void prep_kernel(const float4* __restrict__ x4, unsigned short* __restrict__ Xbf,
                 const float* __restrict__ Wq, const float* __restrict__ Wk,
                 const float* __restrict__ Wv,
                 const float* __restrict__ Aq, const float* __restrict__ Bq,
                 const float* __restrict__ Ak, const float* __restrict__ Bk,
                 const float* __restrict__ Av, const float* __restrict__ Bv,
                 unsigned short* __restrict__ Wf) {
    __shared__ float AsT[16 * AT_STRIDE];   // ~33 KB: A^T chunk, [r][h_local]
    __shared__ float Bsc[64 * 16];          // 4 KB: 2*B[r, n0+..] as [n][r]

    const int tid = threadIdx.x;

    if (blockIdx.x >= WEFF_BLOCKS) {
        int i = (blockIdx.x - WEFF_BLOCKS) * 256 + tid;
        const int stride = CVT_BLOCKS * 256;
        const int n4 = Mdim * Kdim / 4;
        ushort4* out = (ushort4*)Xbf;
        for (; i < n4; i += stride) {
            float4 v = x4[i];
            ushort4 u;
            u.x = f2bf(v.x); u.y = f2bf(v.y); u.z = f2bf(v.z); u.w = f2bf(v.w);
            out[i] = u;
        }
        return;
    }

    const int n0 = (blockIdx.x >> 3) * 64;      // 64-row group (never straddles seg)
    const int h0 = (blockIdx.x & 7) * 512;

    const float* W; const float* A; const float* Bm; int O; int nn0;
    if (n0 < NQ)            { W = Wq; A = Aq; Bm = Bq; O = NQ;  nn0 = n0; }
    else if (n0 < NQ + NKV) { W = Wk; A = Ak; Bm = Bk; O = NKV; nn0 = n0 - NQ; }
    else                    { W = Wv; A = Av; Bm = Bv; O = NKV; nn0 = n0 - NQ - NKV; }

    {
        const float4* Af4 = (const float4*)(A) + h0 * 4;
        #pragma unroll
        for (int i = 0; i < 8; ++i) {
            const int f = i * 256 + tid;
            const float4 v = Af4[f];
            const int hl = f >> 2;
            const int r0 = (f & 3) * 4;
            AsT[(r0 + 0) * AT_STRIDE + hl] = v.x;
            AsT[(r0 + 1) * AT_STRIDE + hl] = v.y;
            AsT[(r0 + 2) * AT_STRIDE + hl] = v.z;
            AsT[(r0 + 3) * AT_STRIDE + hl] = v.w;
        }
    }
    {
        const int nl = tid & 63;
        const int rq = tid >> 6;        // 0..3
        #pragma unroll
        for (int j = 0; j < 4; ++j) {
            const int r = rq * 4 + j;
            Bsc[nl * 16 + r] = Bm[r * O + nn0 + nl] * LORA_SCALE;
        }
    }
    __syncthreads();

    const int wv_ = tid >> 6;
    const int lane = tid & 63;

    #pragma unroll
    for (int pass = 0; pass < 2; ++pass) {
        const int hl = pass * 256 + lane * 4;
        float4 areg[16];
        #pragma unroll
        for (int r = 0; r < 16; ++r)
            areg[r] = *(const float4*)(&AsT[r * AT_STRIDE + hl]);

        for (int i = 0; i < 16; ++i) {
            const int nl = wv_ * 16 + i;
            const float4 w4 = *(const float4*)(W + (size_t)(nn0 + nl) * Kdim + h0 + hl);
            const float4* b4 = (const float4*)(&Bsc[nl * 16]);
            float4 d = {0.f, 0.f, 0.f, 0.f};
            #pragma unroll
            for (int q = 0; q < 4; ++q) {
                const float4 b = b4[q];
                d.x += areg[q*4+0].x * b.x + areg[q*4+1].x * b.y + areg[q*4+2].x * b.z + areg[q*4+3].x * b.w;
                d.y += areg[q*4+0].y * b.x + areg[q*4+1].y * b.y + areg[q*4+2].y * b.z + areg[q*4+3].y * b.w;
                d.z += areg[q*4+0].z * b.x + areg[q*4+1].z * b.y + areg[q*4+2].z * b.z + areg[q*4+3].z * b.w;
                d.w += areg[q*4+0].w * b.x + areg[q*4+1].w * b.y + areg[q*4+2].w * b.z + areg[q*4+3].w * b.w;
            }
            ushort4 u;
            u.x = f2bf(w4.x + d.x); u.y = f2bf(w4.y + d.y);
            u.z = f2bf(w4.z + d.z); u.w = f2bf(w4.w + d.w);
            *(ushort4*)(Wf + (size_t)(n0 + nl) * Kdim + h0 + hl) = u;
        }
    }
}

// ---------------------------------------------------------------------------
// GEMM: out[M, NTOT] = Xbf[M,K] . Wf[NTOT,K]^T + bias, scattered to q/k/v.
//
// LDS (k-major blocks): slice slot = 16 KB; A-slice = [half][w][1KB block]
// where block (half,w) holds rows half*128 + w*16 + (0..15) of one 32-k slice,
// stored k-major: byte (kc*256 + r*16 + 2*j) = element (row r, k = kc*8+j).
// Staging: wave w's global_load_lds (lane -> lane*16) with source
// row = base + w*16 + (lane&15), k = s*32 + (lane>>4)*8 lands exactly k-major.
// Frag read (16x16x32 layout: row=lane&15, k=(lane>>4)*8+j) is then
// base + lane*16 — contiguous 1 KB, bank-uniform, zero swizzle math.
//
// Phase s (one per K-slice): 8 A-frag + 4 B-frag ds_read_b128; stage slice
// s+3 (4 gloads); s_barrier; lgkmcnt(0); setprio(1); 32 MFMA; setprio(0);
// vmcnt(8); s_barrier.
// vmcnt ledger (loads in 4-load slice groups, issue order = slice order):
//   steady state at phase s end: outstanding {s+1,s+2,s+3} = 12 loads;
//   vmcnt(8) retires slice s+1 (issued at phase s-2) -> ready for phase s+1.
//   Prologue: stage 0,1,2; vmcnt(8) lands slice 0. Tail: s=124 stages 127,
//   vmcnt(8) lands 125; s=125 vmcnt(4) lands 126; s=126 vmcnt(0) lands 127.
// WAR: stage targets slot (s+3)&3, reads target slot s&3 — disjoint; slot
// reuse ordered by the end-of-phase barrier.
// ---------------------------------------------------------------------------
__global__ __launch_bounds__(512, 2)
void gemm_qkv_kernel(const unsigned short* __restrict__ X,
                     const unsigned short* __restrict__ Wf,
                     const float* __restrict__ bq, const float* __restrict__ bk,
                     const float* __restrict__ bv,
                     float* __restrict__ out) {
    __shared__ __align__(16) unsigned short Abuf[4][8192];  // 64 KB
    __shared__ __align__(16) unsigned short Bbuf[4][8192];  // 64 KB

    const int tid  = threadIdx.x;
    const int lane = tid & 63;
    const int w    = tid >> 6;
    const int wr   = w >> 2;        // 0..1  (M half)
    const int wc   = w & 3;         // 0..3  (N quarter)

    int bid = blockIdx.x;
    bid = (bid & 7) * (NWG / 8) + (bid >> 3);   // XCD-aware, bijective (768%8==0)
    const int row0 = (bid / TILES_N) * BM;
    const int col0 = (bid % TILES_N) * BN;

    // frag read bases (k-major blocks): contiguous base + lane*16
    const int lane16 = lane * 16;
    const int aBase0 = wr * 8192 + lane16;                       // + mf*1024
    const int bBase0 = (wc >> 1) * 8192 + (wc & 1) * 4096 + lane16;  // + nf*1024

    // staging source addressing (k-major within 16-row group)
    const int srow = w * 16 + (lane & 15);
    const int kofs = (lane >> 4) * 8;
    const unsigned short* pA0 = X  + (size_t)(row0 + srow) * Kdim + kofs;
    const unsigned short* pA1 = pA0 + (size_t)128 * Kdim;
    const unsigned short* pB0 = Wf + (size_t)(col0 + srow) * Kdim + kofs;
    const unsigned short* pB1 = pB0 + (size_t)128 * Kdim;

    floatx4 acc[8][4];
    #pragma unroll
    for (int i = 0; i < 8; ++i)
        #pragma unroll
        for (int j = 0; j < 4; ++j)
            acc[i][j] = (floatx4){0.f, 0.f, 0.f, 0.f};

#define STAGE4(SS, SLOT)                                                         \
    { const int ss_ = (SS);                                                      \
      __builtin_amdgcn_global_load_lds((const GLOBAL_AS void*)(pA0 + ss_ * 32),  \
          (LDS_AS void*)(&Abuf[SLOT][w * 512]),        16, 0, 0);                \
      __builtin_amdgcn_global_load_lds((const GLOBAL_AS void*)(pA1 + ss_ * 32),  \
          (LDS_AS void*)(&Abuf[SLOT][4096 + w * 512]), 16, 0, 0);                \
      __builtin_amdgcn_global_load_lds((const GLOBAL_AS void*)(pB0 + ss_ * 32),  \
          (LDS_AS void*)(&Bbuf[SLOT][w * 512]),        16, 0, 0);                \
      __builtin_amdgcn_global_load_lds((const GLOBAL_AS void*)(pB1 + ss_ * 32),  \
          (LDS_AS void*)(&Bbuf[SLOT][4096 + w * 512]), 16, 0, 0); }

// WM: 0 none, 1 vmcnt(8), 2 vmcnt(4), 3 vmcnt(0)
#define SLICE_PHASE(SLOT, DOSTAGE, SS, WM)                                       \
    { const char* ab_ = (const char*)Abuf + (SLOT) * 16384 + aBase0;             \
      const char* bb_ = (const char*)Bbuf + (SLOT) * 16384 + bBase0;             \
      short8 af[8]; short8 bfr[4];                                               \
      _Pragma("unroll")                                                          \
      for (int mf = 0; mf < 8; ++mf)                                             \
        af[mf] = *(const short8*)(ab_ + mf * 1024);                              \
      _Pragma("unroll")                                                          \
      for (int nf = 0; nf < 4; ++nf)                                             \
        bfr[nf] = *(const short8*)(bb_ + nf * 1024);                             \
      if (DOSTAGE) STAGE4(SS, (SS) & 3);                                         \
      __builtin_amdgcn_s_barrier();                                              \
      asm volatile("s_waitcnt lgkmcnt(0)");                                      \
      __builtin_amdgcn_s_setprio(1);                                             \
      _Pragma("unroll")                                                          \
      for (int mf = 0; mf < 8; ++mf)                                             \
        _Pragma("unroll")                                                        \
        for (int nf = 0; nf < 4; ++nf)                                           \
          acc[mf][nf] = __builtin_amdgcn_mfma_f32_16x16x32_bf16(                 \
              af[mf], bfr[nf], acc[mf][nf], 0, 0, 0);                            \
      __builtin_amdgcn_s_setprio(0);                                             \
      if ((WM) == 1) asm volatile("s_waitcnt vmcnt(8)" ::: "memory");            \
      if ((WM) == 2) asm volatile("s_waitcnt vmcnt(4)" ::: "memory");            \
      if ((WM) == 3) asm volatile("s_waitcnt vmcnt(0)" ::: "memory");            \
      __builtin_amdgcn_s_barrier(); }

    // ---- prologue: stage slices 0,1,2; land slice 0; keep 1,2 in flight ----
    STAGE4(0, 0);
    STAGE4(1, 1);
    STAGE4(2, 2);
    asm volatile("s_waitcnt vmcnt(8)" ::: "memory");
    __builtin_amdgcn_s_barrier();

    // ---- main loop: slices 0..123, staging 3..126 ----
    for (int j = 0; j < 31; ++j) {
        const int g = j * 4;
        SLICE_PHASE(0, 1, g + 3, 1);
        SLICE_PHASE(1, 1, g + 4, 1);
        SLICE_PHASE(2, 1, g + 5, 1);
        SLICE_PHASE(3, 1, g + 6, 1);
    }
    // ---- tail: slices 124..127 (slot = s&3); only 127 left to stage ----
    SLICE_PHASE(0, 1, 127, 1);   // s=124: stage 127, vmcnt(8) lands 125
    SLICE_PHASE(1, 0, 0,   2);   // s=125: vmcnt(4) lands 126
    SLICE_PHASE(2, 0, 0,   3);   // s=126: vmcnt(0) lands 127
    SLICE_PHASE(3, 0, 0,   0);   // s=127

#undef SLICE_PHASE
#undef STAGE4

    // ---- epilogue: bias + scatter into q/k/v regions ----
    float* obase; int ldo; const float* bias; int cofs;
    if (col0 < NQ) {
        obase = out;                             ldo = NQ;  bias = bq; cofs = 0;
    } else if (col0 < NQ + NKV) {
        obase = out + (size_t)Mdim * NQ;         ldo = NKV; bias = bk; cofs = NQ;
    } else {
        obase = out + (size_t)Mdim * (NQ + NKV); ldo = NKV; bias = bv; cofs = NQ + NKV;
    }

    #pragma unroll
    for (int nf = 0; nf < 4; ++nf) {
        const int col = col0 + wc * 64 + nf * 16 + (lane & 15) - cofs;
        const float b = bias[col];
        #pragma unroll
        for (int mf = 0; mf < 8; ++mf) {
            #pragma unroll
            for (int r = 0; r < 4; ++r) {
                const int row = row0 + wr * 128 + mf * 16 + (lane >> 4) * 4 + r;
                obase[(size_t)row * ldo + col] = acc[mf][nf][r] + b;
            }
        }
    }
}

// ---------------------------------------------------------------------------
extern "C" void kernel_launch(void* const* d_in, const int* in_sizes, int n_in,
                              void* d_out, int out_size, void* d_ws, size_t ws_size,
                              hipStream_t stream) {
    const float* x  = (const float*)d_in[0];
    const float* Wq = (const float*)d_in[1];
    const float* Wk = (const float*)d_in[2];
    const float* Wv = (const float*)d_in[3];
    const float* bq = (const float*)d_in[4];
    const float* bk = (const float*)d_in[5];
    const float* bv = (const float*)d_in[6];
    const float* Aq = (const float*)d_in[7];
    const float* Bq = (const float*)d_in[8];
    const float* Ak = (const float*)d_in[9];
    const float* Bk = (const float*)d_in[10];
    const float* Av = (const float*)d_in[11];
    const float* Bv = (const float*)d_in[12];
    float* out = (float*)d_out;

    unsigned short* Xbf = (unsigned short*)d_ws;                   // 64 MB
    unsigned short* Wf  = Xbf + (size_t)Mdim * Kdim;               // 48 MB

    prep_kernel<<<WEFF_BLOCKS + CVT_BLOCKS, 256, 0, stream>>>(
        (const float4*)x, Xbf, Wq, Wk, Wv, Aq, Bq, Ak, Bk, Av, Bv, Wf);

    gemm_qkv_kernel<<<NWG, 512, 0, stream>>>(Xbf, Wf, bq, bk, bv, out);
}

// Round 9
// 552.392 us; speedup vs baseline: 1.0454x; 1.0454x over previous
//
#include <hip/hip_runtime.h>

// ---------------------------------------------------------------------------
// LoRA QKV fused projection on MI355X (gfx950)
// Weff-folding (LoRA into weights) + ONE bf16 MFMA GEMM.
// R9 = R4's exact 2-phase-per-slice schedule (best measured: 397us GEMM)
//      + 32x32x16 MFMA frags (matrix pipe -17%, half the MFMA issues; operand
//        and C/D layouts verified correct in R5)
//      + k-major 32-row LDS blocks (R8-verified staging pattern): every frag
//        read is base + lane*16 -> contiguous 1KB, conflict-free, no swizzle
//        math (fixes R5's 3.78e7 bank conflicts without R6's b64 splitting)
//      + nontemporal epilogue stores (201MB fp32 out streams past LLC; total
//        footprint 313MB > 256MB LLC explains FETCH=7x compulsory)
// ---------------------------------------------------------------------------

#define GLOBAL_AS __attribute__((address_space(1)))
#define LDS_AS    __attribute__((address_space(3)))

typedef __attribute__((ext_vector_type(8)))  short short8;   // 8 bf16 (MFMA A/B frag)
typedef __attribute__((ext_vector_type(16))) float f32x16;   // 32x32 MFMA C/D frag

constexpr int Mdim = 8192;   // B*S
constexpr int Kdim = 4096;   // H
constexpr int NQ   = 4096;
constexpr int NKV  = 1024;
constexpr int NTOT = NQ + 2 * NKV;  // 6144
constexpr float LORA_SCALE = 2.0f;

constexpr int BM = 256, BN = 256;
constexpr int TILES_M = Mdim / BM;      // 32
constexpr int TILES_N = NTOT / BN;      // 24
constexpr int NWG = TILES_M * TILES_N;  // 768 (%8==0 -> bijective XCD swizzle)
constexpr int NSLICE = Kdim / 32;       // 128 K-slices of 32

constexpr int WEFF_BLOCKS = (NTOT / 64) * (Kdim / 512);  // 768
constexpr int CVT_BLOCKS  = 2048;
constexpr int AT_STRIDE   = 516;

__device__ __forceinline__ unsigned short f2bf(float f) {
    union { float f; unsigned int u; } a; a.f = f;
    unsigned int r = a.u + 0x7FFFu + ((a.u >> 16) & 1u);
    return (unsigned short)(r >> 16);
}

// ---------------------------------------------------------------------------
// Fused prep (identical to R4 — linear row-major outputs):
//   blocks [0, WEFF_BLOCKS): Weff[n,h] = W[n,h] + 2*sum_r A[h,r]B[r,n] -> bf16
//   blocks [WEFF_BLOCKS, +CVT_BLOCKS): X fp32 -> bf16.
// ---------------------------------------------------------------------------
__global__ __launch_bounds__(256)
void prep_kernel(const float4* __restrict__ x4, unsigned short* __restrict__ Xbf,
                 const float* __restrict__ Wq, const float* __restrict__ Wk,
                 const float* __restrict__ Wv,
                 const float* __restrict__ Aq, const float* __restrict__ Bq,
                 const float* __restrict__ Ak, const float* __restrict__ Bk,
                 const float* __restrict__ Av, const float* __restrict__ Bv,
                 unsigned short* __restrict__ Wf) {
    __shared__ float AsT[16 * AT_STRIDE];   // ~33 KB: A^T chunk, [r][h_local]
    __shared__ float Bsc[64 * 16];          // 4 KB: 2*B[r, n0+..] as [n][r]

    const int tid = threadIdx.x;

    if (blockIdx.x >= WEFF_BLOCKS) {
        int i = (blockIdx.x - WEFF_BLOCKS) * 256 + tid;
        const int stride = CVT_BLOCKS * 256;
        const int n4 = Mdim * Kdim / 4;
        ushort4* out = (ushort4*)Xbf;
        for (; i < n4; i += stride) {
            float4 v = x4[i];
            ushort4 u;
            u.x = f2bf(v.x); u.y = f2bf(v.y); u.z = f2bf(v.z); u.w = f2bf(v.w);
            out[i] = u;
        }
        return;
    }

    const int n0 = (blockIdx.x >> 3) * 64;      // 64-row group (never straddles seg)
    const int h0 = (blockIdx.x & 7) * 512;

    const float* W; const float* A; const float* Bm; int O; int nn0;
    if (n0 < NQ)            { W = Wq; A = Aq; Bm = Bq; O = NQ;  nn0 = n0; }
    else if (n0 < NQ + NKV) { W = Wk; A = Ak; Bm = Bk; O = NKV; nn0 = n0 - NQ; }
    else                    { W = Wv; A = Av; Bm = Bv; O = NKV; nn0 = n0 - NQ - NKV; }

    {
        const float4* Af4 = (const float4*)(A) + h0 * 4;
        #pragma unroll
        for (int i = 0; i < 8; ++i) {
            const int f = i * 256 + tid;
            const float4 v = Af4[f];
            const int hl = f >> 2;
            const int r0 = (f & 3) * 4;
            AsT[(r0 + 0) * AT_STRIDE + hl] = v.x;
            AsT[(r0 + 1) * AT_STRIDE + hl] = v.y;
            AsT[(r0 + 2) * AT_STRIDE + hl] = v.z;
            AsT[(r0 + 3) * AT_STRIDE + hl] = v.w;
        }
    }
    {
        const int nl = tid & 63;
        const int rq = tid >> 6;        // 0..3
        #pragma unroll
        for (int j = 0; j < 4; ++j) {
            const int r = rq * 4 + j;
            Bsc[nl * 16 + r] = Bm[r * O + nn0 + nl] * LORA_SCALE;
        }
    }
    __syncthreads();

    const int wv_ = tid >> 6;
    const int lane = tid & 63;

    #pragma unroll
    for (int pass = 0; pass < 2; ++pass) {
        const int hl = pass * 256 + lane * 4;
        float4 areg[16];
        #pragma unroll
        for (int r = 0; r < 16; ++r)
            areg[r] = *(const float4*)(&AsT[r * AT_STRIDE + hl]);

        for (int i = 0; i < 16; ++i) {
            const int nl = wv_ * 16 + i;
            const float4 w4 = *(const float4*)(W + (size_t)(nn0 + nl) * Kdim + h0 + hl);
            const float4* b4 = (const float4*)(&Bsc[nl * 16]);
            float4 d = {0.f, 0.f, 0.f, 0.f};
            #pragma unroll
            for (int q = 0; q < 4; ++q) {
                const float4 b = b4[q];
                d.x += areg[q*4+0].x * b.x + areg[q*4+1].x * b.y + areg[q*4+2].x * b.z + areg[q*4+3].x * b.w;
                d.y += areg[q*4+0].y * b.x + areg[q*4+1].y * b.y + areg[q*4+2].y * b.z + areg[q*4+3].y * b.w;
                d.z += areg[q*4+0].z * b.x + areg[q*4+1].z * b.y + areg[q*4+2].z * b.z + areg[q*4+3].z * b.w;
                d.w += areg[q*4+0].w * b.x + areg[q*4+1].w * b.y + areg[q*4+2].w * b.z + areg[q*4+3].w * b.w;
            }
            ushort4 u;
            u.x = f2bf(w4.x + d.x); u.y = f2bf(w4.y + d.y);
            u.z = f2bf(w4.z + d.z); u.w = f2bf(w4.w + d.w);
            *(ushort4*)(Wf + (size_t)(n0 + nl) * Kdim + h0 + hl) = u;
        }
    }
}

// ---------------------------------------------------------------------------
// GEMM: out[M, NTOT] = Xbf[M,K] . Wf[NTOT,K]^T + bias, scattered to q/k/v.
//
// LDS (k-major 32-row blocks): slice slot = 16 KB = 16 blocks of 1 KB.
// Block g32 = rowgroup32*2 + kc holds rows rowgroup32*32+(0..31), k-chunk
// kc*16+(0..15), stored so byte (kh*32 + r)*16 + 2j = element (row r,
// k = kc*16 + kh*8 + j). Staging wave w (lane l -> dest byte l*16) with
// source row = base + w*32 + (l&31), k = s*32 + kc*16 + (l>>5)*8 lands this
// exactly; frag read for mfma_32x32x16 (lane l: row l&31, k (l>>5)*8+j) is
// block_base + l*16 — contiguous 1 KB, conflict-free, zero index math.
//
// Schedule = R4 verbatim (2 phases per slice; ph0 reads A-half0 + all B and
// stages A(s+3); ph1 reads A-half1 and stages B(s+3); barrier; lgkmcnt(0);
// setprio(1); 8 MFMA_32x32; setprio(0); vmcnt(4) at ph3/ph7; barrier).
// vmcnt ledger identical to R4 (2 gloads per STAGE, 4 per slice). Peeled
// last iter: stage only 127 at ph0/ph1; vmcnt(4)@ph3 lands 126, vmcnt(0)@ph5
// lands 127.
// ---------------------------------------------------------------------------
__global__ __launch_bounds__(512, 2)
void gemm_qkv_kernel(const unsigned short* __restrict__ X,
                     const unsigned short* __restrict__ Wf,
                     const float* __restrict__ bq, const float* __restrict__ bk,
                     const float* __restrict__ bv,
                     float* __restrict__ out) {
    __shared__ __align__(16) unsigned short Abuf[4][8192];  // 64 KB
    __shared__ __align__(16) unsigned short Bbuf[4][8192];  // 64 KB

    const int tid  = threadIdx.x;
    const int lane = tid & 63;
    const int w    = tid >> 6;
    const int wr   = w >> 2;        // 0..1  (M half)
    const int wc   = w & 3;         // 0..3  (N quarter)

    int bid = blockIdx.x;
    bid = (bid & 7) * (NWG / 8) + (bid >> 3);   // XCD-aware, bijective (768%8==0)
    const int row0 = (bid / TILES_N) * BM;
    const int col0 = (bid % TILES_N) * BN;

    // frag read bases: block g32 at g32*1024 bytes; lane offset lane*16.
    // A: g32 = (wr*4 + mfg)*2 + ks ; B: g32 = (wc*2 + nf)*2 + ks
    const int lane16 = lane * 16;
    const int aBase0 = wr * 8192 + lane16;   // + (mfg*2+ks)*1024
    const int bBase0 = wc * 4096 + lane16;   // + (nf*2+ks)*1024

    // staging source addressing (k-major within 32-row group; fully linear)
    const int srow = w * 32 + (lane & 31);
    const int kofs = (lane >> 5) * 8;
    const unsigned short* pA = X  + (size_t)(row0 + srow) * Kdim + kofs;
    const unsigned short* pB = Wf + (size_t)(col0 + srow) * Kdim + kofs;

    f32x16 acc[4][2];
    #pragma unroll
    for (int i = 0; i < 4; ++i)
        #pragma unroll
        for (int j = 0; j < 2; ++j)
            acc[i][j] = (f32x16)(0.f);

    short8 bfr[2][2];

// STAGE: MATA=1 stages A-slice (kc=0,1), else B-slice, into slot (SS)&3.
#define STAGE(MATA, SS)                                                          \
    { const int ss_ = (SS); const int st_ = (SS) & 3;                            \
      if (MATA) {                                                                \
        __builtin_amdgcn_global_load_lds((const GLOBAL_AS void*)(pA + ss_ * 32), \
            (LDS_AS void*)(&Abuf[st_][(w * 2 + 0) * 512]), 16, 0, 0);            \
        __builtin_amdgcn_global_load_lds((const GLOBAL_AS void*)(pA + ss_ * 32 + 16), \
            (LDS_AS void*)(&Abuf[st_][(w * 2 + 1) * 512]), 16, 0, 0);            \
      } else {                                                                   \
        __builtin_amdgcn_global_load_lds((const GLOBAL_AS void*)(pB + ss_ * 32), \
            (LDS_AS void*)(&Bbuf[st_][(w * 2 + 0) * 512]), 16, 0, 0);            \
        __builtin_amdgcn_global_load_lds((const GLOBAL_AS void*)(pB + ss_ * 32 + 16), \
            (LDS_AS void*)(&Bbuf[st_][(w * 2 + 1) * 512]), 16, 0, 0);            \
      } }

// WAITMODE: 0 none, 1 vmcnt(4), 2 vmcnt(0)
#define DO_PHASE(G, MH, DOSTAGE, SMATA, SS, WAITMODE)                            \
    {                                                                            \
      const int slot_ = (G) & 3;                                                 \
      const char* abase_ = (const char*)Abuf + slot_ * 16384;                    \
      short8 af[2][2];                                                           \
      _Pragma("unroll")                                                          \
      for (int m = 0; m < 2; ++m)                                                \
        _Pragma("unroll")                                                        \
        for (int ks = 0; ks < 2; ++ks)                                           \
          af[m][ks] = *(const short8*)(abase_ + aBase0 +                         \
                          (((MH) * 2 + m) * 2 + ks) * 1024);                     \
      if ((MH) == 0) {                                                           \
        const char* bbase_ = (const char*)Bbuf + slot_ * 16384;                  \
        _Pragma("unroll")                                                        \
        for (int n = 0; n < 2; ++n)                                              \
          _Pragma("unroll")                                                      \
          for (int ks = 0; ks < 2; ++ks)                                         \
            bfr[n][ks] = *(const short8*)(bbase_ + bBase0 + (n * 2 + ks) * 1024);\
      }                                                                          \
      if (DOSTAGE) STAGE(SMATA, SS);                                             \
      __builtin_amdgcn_s_barrier();                                              \
      asm volatile("s_waitcnt lgkmcnt(0)");                                      \
      __builtin_amdgcn_s_setprio(1);                                             \
      _Pragma("unroll")                                                          \
      for (int ks = 0; ks < 2; ++ks)                                             \
        _Pragma("unroll")                                                        \
        for (int m = 0; m < 2; ++m)                                              \
          _Pragma("unroll")                                                      \
          for (int n = 0; n < 2; ++n)                                            \
            acc[(MH) * 2 + m][n] = __builtin_amdgcn_mfma_f32_32x32x16_bf16(      \
                af[m][ks], bfr[n][ks], acc[(MH) * 2 + m][n], 0, 0, 0);           \
      __builtin_amdgcn_s_setprio(0);                                             \
      if ((WAITMODE) == 1) asm volatile("s_waitcnt vmcnt(4)" ::: "memory");      \
      if ((WAITMODE) == 2) asm volatile("s_waitcnt vmcnt(0)" ::: "memory");      \
      __builtin_amdgcn_s_barrier();                                              \
    }

    // ---- prologue: stage slices 0,1,2; land 0 and 1; keep 2 in flight ----
    STAGE(1, 0); STAGE(0, 0);
    STAGE(1, 1); STAGE(0, 1);
    STAGE(1, 2); STAGE(0, 2);
    asm volatile("s_waitcnt vmcnt(4)" ::: "memory");
    __builtin_amdgcn_s_barrier();

    for (int j = 0; j < NSLICE / 4 - 1; ++j) {
        const int g0 = j * 4;
        DO_PHASE(g0 + 0, 0, 1, 1, g0 + 3, 0);
        DO_PHASE(g0 + 0, 1, 1, 0, g0 + 3, 0);
        DO_PHASE(g0 + 1, 0, 1, 1, g0 + 4, 0);
        DO_PHASE(g0 + 1, 1, 1, 0, g0 + 4, 1);
        DO_PHASE(g0 + 2, 0, 1, 1, g0 + 5, 0);
        DO_PHASE(g0 + 2, 1, 1, 0, g0 + 5, 0);
        DO_PHASE(g0 + 3, 0, 1, 1, g0 + 6, 0);
        DO_PHASE(g0 + 3, 1, 1, 0, g0 + 6, 1);
    }
    // ---- peeled last iteration (g0 = 124): stage only slice 127 ----
    DO_PHASE(124, 0, 1, 1, 127, 0);
    DO_PHASE(124, 1, 1, 0, 127, 0);
    DO_PHASE(125, 0, 0, 0, 0,   0);
    DO_PHASE(125, 1, 0, 0, 0,   1);   // lands slice 126
    DO_PHASE(126, 0, 0, 0, 0,   0);
    DO_PHASE(126, 1, 0, 0, 0,   2);   // lands slice 127
    DO_PHASE(127, 0, 0, 0, 0,   0);
    DO_PHASE(127, 1, 0, 0, 0,   0);

#undef DO_PHASE
#undef STAGE

    // ---- epilogue: bias + scatter into q/k/v regions (nontemporal) ----
    float* obase; int ldo; const float* bias; int cofs;
    if (col0 < NQ) {
        obase = out;                             ldo = NQ;  bias = bq; cofs = 0;
    } else if (col0 < NQ + NKV) {
        obase = out + (size_t)Mdim * NQ;         ldo = NKV; bias = bk; cofs = NQ;
    } else {
        obase = out + (size_t)Mdim * (NQ + NKV); ldo = NKV; bias = bv; cofs = NQ + NKV;
    }

    #pragma unroll
    for (int nf = 0; nf < 2; ++nf) {
        const int col = col0 + wc * 64 + nf * 32 + (lane & 31) - cofs;
        const float b = bias[col];
        #pragma unroll
        for (int mf = 0; mf < 4; ++mf) {
            #pragma unroll
            for (int r = 0; r < 16; ++r) {
                const int row = row0 + wr * 128 + mf * 32
                              + ((lane >> 5) << 2) + (r & 3) + ((r >> 2) << 3);
                __builtin_nontemporal_store(acc[mf][nf][r] + b,
                                            &obase[(size_t)row * ldo + col]);
            }
        }
    }
}

// ---------------------------------------------------------------------------
extern "C" void kernel_launch(void* const* d_in, const int* in_sizes, int n_in,
                              void* d_out, int out_size, void* d_ws, size_t ws_size,
                              hipStream_t stream) {
    const float* x  = (const float*)d_in[0];
    const float* Wq = (const float*)d_in[1];
    const float* Wk = (const float*)d_in[2];
    const float* Wv = (const float*)d_in[3];
    const float* bq = (const float*)d_in[4];
    const float* bk = (const float*)d_in[5];
    const float* bv = (const float*)d_in[6];
    const float* Aq = (const float*)d_in[7];
    const float* Bq = (const float*)d_in[8];
    const float* Ak = (const float*)d_in[9];
    const float* Bk = (const float*)d_in[10];
    const float* Av = (const float*)d_in[11];
    const float* Bv = (const float*)d_in[12];
    float* out = (float*)d_out;

    unsigned short* Xbf = (unsigned short*)d_ws;                   // 64 MB
    unsigned short* Wf  = Xbf + (size_t)Mdim * Kdim;               // 48 MB

    prep_kernel<<<WEFF_BLOCKS + CVT_BLOCKS, 256, 0, stream>>>(
        (const float4*)x, Xbf, Wq, Wk, Wv, Aq, Bq, Ak, Bk, Av, Bv, Wf);

    gemm_qkv_kernel<<<NWG, 512, 0, stream>>>(Xbf, Wf, bq, bk, bv, out);
}